// Round 3
// baseline (808.944 us; speedup 1.0000x reference)
//
#include <hip/hip_runtime.h>

#define N 1024
#define F 32
#define H 64
#define EA 8

typedef const __attribute__((address_space(1))) void global_cv;
typedef __attribute__((address_space(3))) void lds_v;

// async global->LDS: 64 lanes x 16B, dest = wave-uniform LDS base + lane*16
__device__ __forceinline__ void stage_1kb(const float* g, float* l, int lane) {
    __builtin_amdgcn_global_load_lds((global_cv*)(g + lane * 4), (lds_v*)l, 16, 0, 0);
}
// stage one 2KB row chunk (64 w x 8 floats)
__device__ __forceinline__ void stage_row(const float* g, float* l, int lane) {
    stage_1kb(g, l, lane);
    stage_1kb(g + 256, l + 256, lane);
}

// Kernel 1: sv[v,h] = b[h] + sum_f X[v,f]*(W[f,h]-W[32+f,h]); nb[v,h] = sum_f X[v,f]*W[32+f,h]
// Also zeroes out[]. One wave per v; lane = h. grid 256 x 256 threads.
__global__ __launch_bounds__(256) void precompute_terms(
    const float* __restrict__ X, const float* __restrict__ W, const float* __restrict__ b,
    float* __restrict__ sv, float* __restrict__ nb, float* __restrict__ out)
{
    const int lane = threadIdx.x & 63;
    const int wid  = threadIdx.x >> 6;
    const int v    = blockIdx.x * 4 + wid;

    // X row: 32 floats, broadcast loads issued independently (one latency round)
    float4 xr[8];
    const float4* xp = (const float4*)(X + (size_t)v * F);
#pragma unroll
    for (int i = 0; i < 8; ++i) xr[i] = xp[i];
    const float* xf = (const float*)xr;

    float s = b[lane];
    float n = 0.f;
#pragma unroll
    for (int f = 0; f < F; ++f) {
        float ws = W[f * H + lane];          // 64 independent coalesced loads,
        float wd = W[(F + f) * H + lane];    // compiler hoists & pipelines them
        s = fmaf(xf[f], ws - wd, s);
        n = fmaf(xf[f], wd, n);
    }
    const int idx = v * H + lane;
    sv[idx]  = s;
    nb[idx]  = n;
    out[idx] = 0.f;
}

// Kernel 2: wave = 64 h-channels, 2 v-rows per wave, 2 chunks of 64 w per wave.
// E staged via async global_load_lds into wave-private LDS double buffers.
// grid = 128 vgroups * 8 wsplits = 1024 blocks, 256 threads.
__global__ __launch_bounds__(256) void edge_aggregate(
    const int* __restrict__ A, const float* __restrict__ Edge, const float* __restrict__ W,
    const float* __restrict__ sv, const float* __restrict__ nb, float* __restrict__ out)
{
    const int lane  = threadIdx.x & 63;
    const int wid   = threadIdx.x >> 6;
    const int split = blockIdx.x & 7;
    const int vgrp  = blockIdx.x >> 3;

    const int v0   = vgrp * 8 + wid * 2;
    const int v1   = v0 + 1;
    const int wseg = split * 128;

    __shared__ float eb[4][2][2][512];   // [wave][buf][row][64w*8e] = 32 KB

    float wc[EA];
#pragma unroll
    for (int e = 0; e < EA; ++e) wc[e] = W[(2 * F + e) * H + lane];

    const float s0 = sv[v0 * H + lane];
    const float s1 = sv[v1 * H + lane];

    // A masks for both chunks, as per-lane floats (broadcast later via readlane-shfl)
    const float a0c0 = (float)A[(size_t)v0 * N + wseg + lane];
    const float a1c0 = (float)A[(size_t)v1 * N + wseg + lane];
    const float a0c1 = (float)A[(size_t)v0 * N + wseg + 64 + lane];
    const float a1c1 = (float)A[(size_t)v1 * N + wseg + 64 + lane];

    const float* e0base = Edge + (size_t)v0 * N * EA;
    const float* e1base = Edge + (size_t)v1 * N * EA;

    // stage chunk 0 into buf 0
    stage_row(e0base + (size_t)wseg * EA, &eb[wid][0][0][0], lane);
    stage_row(e1base + (size_t)wseg * EA, &eb[wid][0][1][0], lane);

    // nb rolling window: prologue j=0..15 of chunk 0
    float nbwin[16];
#pragma unroll
    for (int p = 0; p < 16; ++p) nbwin[p] = nb[(size_t)(wseg + p) * H + lane];

    __builtin_amdgcn_s_waitcnt(0);          // buf0 staged, prologue drained
    __builtin_amdgcn_sched_barrier(0);

    // stage chunk 1 into buf 1 (flies under chunk-0 compute)
    stage_row(e0base + (size_t)(wseg + 64) * EA, &eb[wid][1][0][0], lane);
    stage_row(e1base + (size_t)(wseg + 64) * EA, &eb[wid][1][1][0], lane);

    float acc0 = 0.f, acc1 = 0.f;

#pragma unroll
    for (int c = 0; c < 2; ++c) {
        const float* eL0 = &eb[wid][c][0][0];
        const float* eL1 = &eb[wid][c][1][0];
        const float av0 = c ? a0c1 : a0c0;
        const float av1 = c ? a1c1 : a1c0;
        const int wbase = wseg + c * 64;

#pragma unroll
        for (int jo = 0; jo < 8; ++jo) {
#pragma unroll
            for (int jj = 0; jj < 8; ++jj) {
                const int j = jo * 8 + jj;
                const float am0 = __shfl(av0, j, 64);   // constant lane -> readlane
                const float am1 = __shfl(av1, j, 64);
                const float4 x0 = *(const float4*)&eL0[j * 8];
                const float4 y0 = *(const float4*)&eL0[j * 8 + 4];
                const float4 x1 = *(const float4*)&eL1[j * 8];
                const float4 y1 = *(const float4*)&eL1[j * 8 + 4];
                const float nbv = nbwin[j & 15];

                float t0 = s0 + nbv;
                t0 = fmaf(x0.x, wc[0], t0); t0 = fmaf(x0.y, wc[1], t0);
                t0 = fmaf(x0.z, wc[2], t0); t0 = fmaf(x0.w, wc[3], t0);
                t0 = fmaf(y0.x, wc[4], t0); t0 = fmaf(y0.y, wc[5], t0);
                t0 = fmaf(y0.z, wc[6], t0); t0 = fmaf(y0.w, wc[7], t0);
                acc0 = fmaf(am0, fmaxf(t0, 0.f), acc0);

                float t1 = s1 + nbv;
                t1 = fmaf(x1.x, wc[0], t1); t1 = fmaf(x1.y, wc[1], t1);
                t1 = fmaf(x1.z, wc[2], t1); t1 = fmaf(x1.w, wc[3], t1);
                t1 = fmaf(y1.x, wc[4], t1); t1 = fmaf(y1.y, wc[5], t1);
                t1 = fmaf(y1.z, wc[6], t1); t1 = fmaf(y1.w, wc[7], t1);
                acc1 = fmaf(am1, fmaxf(t1, 0.f), acc1);
            }
            // refill slots consumed this block with values for j+16 (crosses into
            // next chunk's first 16 j's at jo=6,7 of chunk 0; tails off in chunk 1)
#pragma unroll
            for (int jj = 0; jj < 8; ++jj) {
                const int jn = jo * 8 + 16 + jj;
                if (c * 64 + jn < 128) {
                    nbwin[(jo * 8 + jj) & 15] = nb[(size_t)(wbase + jn) * H + lane];
                }
            }
        }
        if (c == 0) {
            __builtin_amdgcn_s_waitcnt(0);  // ensure buf1 staged before its ds_reads
            __builtin_amdgcn_sched_barrier(0);
        }
    }

    unsafeAtomicAdd(&out[v0 * H + lane], acc0);
    unsafeAtomicAdd(&out[v1 * H + lane], acc1);
}

extern "C" void kernel_launch(void* const* d_in, const int* in_sizes, int n_in,
                              void* d_out, int out_size, void* d_ws, size_t ws_size,
                              hipStream_t stream) {
    const int*   A    = (const int*)d_in[0];
    const float* X    = (const float*)d_in[1];
    const float* Edge = (const float*)d_in[2];
    const float* W    = (const float*)d_in[3];
    const float* b    = (const float*)d_in[4];
    float* out = (float*)d_out;

    float* sv = (float*)d_ws;
    float* nb = sv + N * H;

    precompute_terms<<<dim3(256), dim3(256), 0, stream>>>(X, W, b, sv, nb, out);
    edge_aggregate<<<dim3(128 * 8), dim3(256), 0, stream>>>(A, Edge, W, sv, nb, out);
}

// Round 4
// 105.956 us; speedup vs baseline: 7.6347x; 7.6347x over previous
//
#include <hip/hip_runtime.h>

#define N 1024
#define F 32
#define H 64
#define EA 8

typedef const __attribute__((address_space(1))) void global_cv;
typedef __attribute__((address_space(3))) void lds_v;

// async global->LDS: 64 lanes x 16B, dest = wave-uniform LDS base + lane*16
__device__ __forceinline__ void stage_1kb(const float* g, float* l, int lane) {
    __builtin_amdgcn_global_load_lds((global_cv*)(g + lane * 4), (lds_v*)l, 16, 0, 0);
}
// stage one 2KB row chunk (64 w x 8 floats)
__device__ __forceinline__ void stage_row(const float* g, float* l, int lane) {
    stage_1kb(g, l, lane);
    stage_1kb(g + 256, l + 256, lane);
}

// Kernel 1: sv[v,h] = b[h] + sum_f X[v,f]*(W[f,h]-W[32+f,h]); nb[v,h] = sum_f X[v,f]*W[32+f,h]
// Also zeroes out[]. One wave per v; lane = h.
__global__ __launch_bounds__(256) void precompute_terms(
    const float* __restrict__ X, const float* __restrict__ W, const float* __restrict__ b,
    float* __restrict__ sv, float* __restrict__ nb, float* __restrict__ out)
{
    const int lane = threadIdx.x & 63;
    const int wid  = threadIdx.x >> 6;
    const int v    = blockIdx.x * 4 + wid;

    float4 xr[8];
    const float4* xp = (const float4*)(X + (size_t)v * F);
#pragma unroll
    for (int i = 0; i < 8; ++i) xr[i] = xp[i];
    const float* xf = (const float*)xr;

    float s = b[lane];
    float n = 0.f;
#pragma unroll
    for (int f = 0; f < F; ++f) {
        float ws = W[f * H + lane];          // coalesced, independent loads
        float wd = W[(F + f) * H + lane];
        s = fmaf(xf[f], ws - wd, s);
        n = fmaf(xf[f], wd, n);
    }
    const int idx = v * H + lane;
    sv[idx]  = s;
    nb[idx]  = n;
    out[idx] = 0.f;
}

// Kernel 2: wave = 64 h-channels, 2 v-rows per wave, 2 chunks of 64 w.
// E async-staged into wave-private LDS double buffers (chunk-deep prefetch).
// A-mask held as wave-uniform 64-bit SGPR via __ballot (no VGPR cost).
// grid = 128 vgroups * 8 wsplits = 1024 blocks, 256 threads, LDS 32KB.
__global__ __launch_bounds__(256) void edge_aggregate(
    const int* __restrict__ A, const float* __restrict__ Edge, const float* __restrict__ W,
    const float* __restrict__ sv, const float* __restrict__ nb, float* __restrict__ out)
{
    const int lane  = threadIdx.x & 63;
    const int wid   = threadIdx.x >> 6;
    const int split = blockIdx.x & 7;
    const int vgrp  = blockIdx.x >> 3;

    const int v0   = vgrp * 8 + wid * 2;
    const int v1   = v0 + 1;
    const int wseg = split * 128;

    __shared__ float eb[4][2][2][512];   // [wave][buf][row][64w*8e] = 32 KB

    float wc[EA];
#pragma unroll
    for (int e = 0; e < EA; ++e) wc[e] = W[(2 * F + e) * H + lane];

    const float s0 = sv[v0 * H + lane];
    const float s1 = sv[v1 * H + lane];

    const float* e0b = Edge + ((size_t)v0 * N + wseg) * EA;
    const float* e1b = Edge + ((size_t)v1 * N + wseg) * EA;

    // stage chunk 0 into buf 0 (4 async 1KB DMAs)
    stage_row(e0b, &eb[wid][0][0][0], lane);
    stage_row(e1b, &eb[wid][0][1][0], lane);

    // adjacency masks for both chunks -> wave-uniform SGPR pairs
    unsigned long long m0c0 = __ballot(A[(size_t)v0 * N + wseg + lane] != 0);
    unsigned long long m1c0 = __ballot(A[(size_t)v1 * N + wseg + lane] != 0);
    unsigned long long m0c1 = __ballot(A[(size_t)v0 * N + wseg + 64 + lane] != 0);
    unsigned long long m1c1 = __ballot(A[(size_t)v1 * N + wseg + 64 + lane] != 0);

    float acc0 = 0.f, acc1 = 0.f;

    for (int c = 0; c < 2; ++c) {
        __builtin_amdgcn_s_waitcnt(0);       // staged buffer ready
        __builtin_amdgcn_sched_barrier(0);
        if (c == 0) {                        // prefetch chunk 1 under chunk-0 compute
            stage_row(e0b + 512, &eb[wid][1][0][0], lane);
            stage_row(e1b + 512, &eb[wid][1][1][0], lane);
        }
        const float* eL0 = &eb[wid][c][0][0];
        const float* eL1 = &eb[wid][c][1][0];
        const unsigned long long mm0 = c ? m0c1 : m0c0;
        const unsigned long long mm1 = c ? m1c1 : m1c0;
        const float* nbp = nb + (size_t)(wseg + c * 64) * H + lane;

#pragma unroll 4
        for (int j = 0; j < 64; ++j) {
            const float nbv = nbp[j * H];               // coalesced, L2-hot
            const float4 x0 = *(const float4*)&eL0[j * 8];   // ds_read_b128 broadcast
            const float4 y0 = *(const float4*)&eL0[j * 8 + 4];
            const float4 x1 = *(const float4*)&eL1[j * 8];
            const float4 y1 = *(const float4*)&eL1[j * 8 + 4];

            float t0 = s0 + nbv;
            t0 = fmaf(x0.x, wc[0], t0); t0 = fmaf(x0.y, wc[1], t0);
            t0 = fmaf(x0.z, wc[2], t0); t0 = fmaf(x0.w, wc[3], t0);
            t0 = fmaf(y0.x, wc[4], t0); t0 = fmaf(y0.y, wc[5], t0);
            t0 = fmaf(y0.z, wc[6], t0); t0 = fmaf(y0.w, wc[7], t0);

            float t1 = s1 + nbv;
            t1 = fmaf(x1.x, wc[0], t1); t1 = fmaf(x1.y, wc[1], t1);
            t1 = fmaf(x1.z, wc[2], t1); t1 = fmaf(x1.w, wc[3], t1);
            t1 = fmaf(y1.x, wc[4], t1); t1 = fmaf(y1.y, wc[5], t1);
            t1 = fmaf(y1.z, wc[6], t1); t1 = fmaf(y1.w, wc[7], t1);

            acc0 += ((mm0 >> j) & 1ull) ? fmaxf(t0, 0.f) : 0.f;
            acc1 += ((mm1 >> j) & 1ull) ? fmaxf(t1, 0.f) : 0.f;
        }
    }

    unsafeAtomicAdd(&out[v0 * H + lane], acc0);
    unsafeAtomicAdd(&out[v1 * H + lane], acc1);
}

extern "C" void kernel_launch(void* const* d_in, const int* in_sizes, int n_in,
                              void* d_out, int out_size, void* d_ws, size_t ws_size,
                              hipStream_t stream) {
    const int*   A    = (const int*)d_in[0];
    const float* X    = (const float*)d_in[1];
    const float* Edge = (const float*)d_in[2];
    const float* W    = (const float*)d_in[3];
    const float* b    = (const float*)d_in[4];
    float* out = (float*)d_out;

    float* sv = (float*)d_ws;
    float* nb = sv + N * H;

    precompute_terms<<<dim3(256), dim3(256), 0, stream>>>(X, W, b, sv, nb, out);
    edge_aggregate<<<dim3(128 * 8), dim3(256), 0, stream>>>(A, Edge, W, sv, nb, out);
}